// Round 11
// baseline (481.382 us; speedup 1.0000x reference)
//
#include <hip/hip_runtime.h>
#include <hip/hip_bf16.h>
#include <stdint.h>

// Spatial local attention, MI355X bf16-MFMA implementation.
// Round 11: (a) softmax stats fused into qk_gemm epilogue (per-slice partials ->
// combine_stats kernel), guarded by ws_size check with round-10 row_stats fallback;
// (b) qkv_conv epilogue halved (26KB LDS union -> 4 blocks/CU instead of 3).
//
// Workspace layout (bytes), base total = 335,806,464 (~320.3 MiB):
//   [0        , 110592   ) Wqkv_t bf16 [9][192][32]
//   [110592   , 184320   ) Wo_t   bf16 [9][64][64]
//   [262144   , 67371008 ) q  bf16 [64][1024][512]   (reused as y_img bf16 [8][256][256][64] channels-last)
//   [67371008 , 134479872) k  bf16 [64][1024][512]   (first 512KB reused as pstats after qk_gemm)
//   [134479872, 268697600) S   bf16 [64][1024][1024] (raw scaled scores; exp applied in pv)
//   [268697600, 335806464) vt bf16 [64][512][1024]   (rows indexed by d' = pyix*8+jj)
//   [335806464, 344195072) OPTIONAL stats partials float2 [64][1024][16] (if ws_size allows)

using bf16 = __hip_bfloat16;
typedef short bf16x8 __attribute__((ext_vector_type(8)));
typedef float f32x4 __attribute__((ext_vector_type(4)));

#define AS1 __attribute__((address_space(1)))
#define AS3 __attribute__((address_space(3)))

__device__ __forceinline__ void gload_lds16(const void* g, void* l) {
  __builtin_amdgcn_global_load_lds((const AS1 unsigned int*)g, (AS3 unsigned int*)l, 16, 0, 0);
}
__device__ __forceinline__ float b2f(unsigned short u) {
  union { unsigned int i; float f; } x; x.i = ((unsigned)u) << 16; return x.f;
}
__device__ __forceinline__ unsigned short f2b(float f) {
  __hip_bfloat16 h = __float2bfloat16(f);
  return *reinterpret_cast<unsigned short*>(&h);
}

// ---------------- weight prep: f32 OIHW -> bf16 [step][co][ci] ----------------
__global__ __launch_bounds__(256) void prep_w(const float* __restrict__ Wq, const float* __restrict__ Wk,
                                              const float* __restrict__ Wv, const float* __restrict__ Wo,
                                              bf16* __restrict__ wt, bf16* __restrict__ wot) {
  int i = blockIdx.x * 256 + threadIdx.x;
  if (i < 9 * 192 * 32) {              // wt[s][co192][ci]
    int ci = i & 31, co192 = (i >> 5) % 192, s = i / 6144;
    int dy = s / 3, dx = s % 3;
    int proj = co192 >> 6, co = co192 & 63;
    const float* Ws = (proj == 0) ? Wq : ((proj == 1) ? Wk : Wv);
    wt[i] = __float2bfloat16(Ws[((co * 32 + ci) * 3 + dy) * 3 + dx]);
  }
  if (i < 9 * 64 * 64) {               // wot[s][co][ci]
    int ci = i & 63, co = (i >> 6) & 63, s = i >> 12;
    wot[i] = __float2bfloat16(Wo[((co * 64 + ci) * 3 + (s / 3)) * 3 + (s % 3)]);
  }
}

// ---------------- QKV windowed conv (round-7 staging; halved epilogue) ----------------
// block: 2 windows (128 px), M=192 (q|k|v x 64co), K = 9 steps x 32ci. 4 waves split M.
// smem union: xp [2*100][40] (8000 el, 16000B) | outl_half [96][136] (13056 el, 26112B).
__global__ __launch_bounds__(256) void qkv_conv(const float* __restrict__ x, const bf16* __restrict__ wt,
                                                const float* __restrict__ bq, const float* __restrict__ bk,
                                                const float* __restrict__ bv,
                                                bf16* __restrict__ qout, bf16* __restrict__ kout,
                                                bf16* __restrict__ vout) {
  __shared__ bf16 smem[13056];
  bf16* xp = smem;
  int tid = threadIdx.x, bid = blockIdx.x;
  int t = bid >> 9, g = bid & 511;
  int gy = g >> 4, gx0 = (g & 15) * 2;

  unsigned int* xp32 = (unsigned int*)xp;
  for (int i = tid; i < 4000; i += 256) xp32[i] = 0u;
  __syncthreads();
  const float* xb = x + (size_t)t * 32 * 65536;
  #pragma unroll
  for (int it = 0; it < 16; ++it) {
    int e = tid + it * 256;
    int ix = e & 7, win = (e >> 3) & 1, iy = (e >> 4) & 7, ci = e >> 7;
    float val = xb[(size_t)ci * 65536 + (gy * 8 + iy) * 256 + (gx0 + win) * 8 + ix];
    xp[(win * 100 + (iy + 1) * 10 + (ix + 1)) * 40 + ci] = __float2bfloat16(val);
  }
  __syncthreads();

  int wv = tid >> 6, l = tid & 63, l15 = l & 15, lg = l >> 4;
  f32x4 z4 = {0.f, 0.f, 0.f, 0.f};
  f32x4 acc[3][8];
  for (int i = 0; i < 3; ++i) for (int j = 0; j < 8; ++j) acc[i][j] = z4;

  #pragma unroll
  for (int s = 0; s < 9; ++s) {
    const int dy = s / 3, dx = s % 3;
    bf16x8 a[3];
    #pragma unroll
    for (int mt = 0; mt < 3; ++mt)
      a[mt] = *(const bf16x8*)&wt[((size_t)s * 192 + wv * 48 + mt * 16 + l15) * 32 + lg * 8];
    #pragma unroll
    for (int nt = 0; nt < 8; ++nt) {
      int n = nt * 16 + l15;
      int win = n >> 6, px = n & 63;
      int iy = px >> 3, ix = px & 7;
      bf16x8 b = *(const bf16x8*)&xp[(win * 100 + (iy + dy) * 10 + (ix + dx)) * 40 + lg * 8];
      #pragma unroll
      for (int mt = 0; mt < 3; ++mt)
        acc[mt][nt] = __builtin_amdgcn_mfma_f32_16x16x32_bf16(a[mt], b, acc[mt][nt], 0, 0, 0);
    }
  }

  // halved epilogue: two passes through outl_half [96][136]
  __syncthreads();                     // xp reads complete; reuse smem as outl
  bf16* outl = smem;
  #pragma unroll
  for (int half = 0; half < 2; ++half) {
    if ((wv >> 1) == half) {           // waves {2*half, 2*half+1} own rows [half*96, half*96+96)
      #pragma unroll
      for (int mt = 0; mt < 3; ++mt) {
        int c0 = wv * 48 + mt * 16 + lg * 4;     // global co192 row (r=0)
        int rl0 = c0 - half * 96;                // local row 0..92
        int proj = c0 >> 6;
        const float* bptr = (proj == 0) ? bq : ((proj == 1) ? bk : bv);
        float bias[4];
        #pragma unroll
        for (int r = 0; r < 4; ++r) bias[r] = bptr[(c0 + r) & 63];
        #pragma unroll
        for (int nt = 0; nt < 8; ++nt) {
          int n = nt * 16 + l15;
          #pragma unroll
          for (int r = 0; r < 4; ++r)
            outl[(rl0 + r) * 136 + n] = __float2bfloat16(acc[mt][nt][r] + bias[r]);
        }
      }
    }
    __syncthreads();
    // all threads store 96 rows x 128 cols = 768 chunks of 16 el (32B each)
    #pragma unroll
    for (int it = 0; it < 3; ++it) {
      int c = it * 256 + tid;
      int row_l = c >> 3, ch = c & 7;
      int grow = half * 96 + row_l;
      int proj = grow >> 6, head = (grow >> 3) & 7, jj = grow & 7;
      int win2 = ch >> 2, px0 = (ch & 3) * 16;
      const bf16* src = &outl[row_l * 136 + win2 * 64 + px0];
      bf16x8 v0 = *(const bf16x8*)src;
      bf16x8 v1 = *(const bf16x8*)(src + 8);
      bf16* dstp = (proj == 0) ? qout : ((proj == 1) ? kout : vout);
      size_t gwin = (size_t)gy * 32 + gx0 + win2;
      bf16* d = &dstp[((size_t)(t * 8 + head) * 1024 + gwin) * 512 + jj * 64 + px0];
      *(bf16x8*)d = v0;
      *(bf16x8*)(d + 8) = v1;
    }
    if (half == 0) __syncthreads();
  }
}

// ---------------- V transpose + d-permute: [bh][win][d=jj*64+pyix] -> [bh][d'=pyix*8+jj][win] ----------------
__global__ __launch_bounds__(256) void transpose_v(const bf16* __restrict__ v, bf16* __restrict__ vt) {
  __shared__ bf16 tl[64 * 72];         // [d_local][win pad72]
  int tid = threadIdx.x, bid = blockIdx.x;
  int bh = bid >> 7, wtile = (bid >> 3) & 15, dtile = bid & 7;   // dtile == jj
  int w0 = wtile * 64, d0 = dtile * 64;
  const bf16* vb = v + ((size_t)bh * 1024 + w0) * 512 + d0;
  int win_l = tid >> 2, dseg = (tid & 3) * 16;
  bf16x8 x0 = *(const bf16x8*)&vb[(size_t)win_l * 512 + dseg];
  bf16x8 x1 = *(const bf16x8*)&vb[(size_t)win_l * 512 + dseg + 8];
  #pragma unroll
  for (int j = 0; j < 8; ++j) {
    *(short*)&tl[(dseg + j) * 72 + win_l] = x0[j];
    *(short*)&tl[(dseg + 8 + j) * 72 + win_l] = x1[j];
  }
  __syncthreads();
  int d_l = tid >> 2, wseg = (tid & 3) * 16;   // d_l == pyix
  bf16x8 y0 = *(const bf16x8*)&tl[d_l * 72 + wseg];
  bf16x8 y1 = *(const bf16x8*)&tl[d_l * 72 + wseg + 8];
  bf16* vtb = vt + ((size_t)bh * 512 + d_l * 8 + dtile) * 1024 + w0 + wseg;
  *(bf16x8*)&vtb[0] = y0;
  *(bf16x8*)&vtb[8] = y1;
}

// ---- shared 256x256 GEMM machinery: 8 waves, BK=64, dbuf, XOR slot swizzle ----
__device__ __forceinline__ void stage8(const bf16* __restrict__ Ab, const bf16* __restrict__ Bb,
                                       bf16* smem, int c, int t, int sk,
                                       int w, int lr, int sl) {
  #pragma unroll
  for (int p = 0; p < 4; ++p) {
    int row = p * 64 + w * 8 + lr;
    gload_lds16(Ab + (size_t)row * sk + t * 64 + sl * 8,
                (char*)smem + c * 65536 + p * 8192 + w * 1024);
    gload_lds16(Bb + (size_t)row * sk + t * 64 + sl * 8,
                (char*)smem + c * 65536 + 32768 + p * 8192 + w * 1024);
  }
}

// ---------------- batched QK^T -> S bf16 (scaled), 256x256 tile + optional stats ----------------
__global__ __launch_bounds__(512, 2) void qk_gemm(const bf16* __restrict__ q, const bf16* __restrict__ k,
                                                  bf16* __restrict__ S, float2* __restrict__ part) {
  __shared__ bf16 smem[65536];         // 128 KiB: 2 bufs x (A 32K + B 32K)
  int tid = threadIdx.x;
  int bid = (blockIdx.x & 7) * 128 + (blockIdx.x >> 3);    // XCD swizzle (1024 % 8 == 0)
  int batch = bid >> 4, tm = (bid >> 2) & 3, tn = bid & 3;
  const bf16* Qb = q + (size_t)batch * 1024 * 512 + (size_t)tm * 256 * 512;
  const bf16* Kb = k + (size_t)batch * 1024 * 512 + (size_t)tn * 256 * 512;
  int w = tid >> 6, l = tid & 63, l15 = l & 15, lg = l >> 4;
  int wm2 = w >> 2, wn4 = w & 3;
  int lr = l >> 3, sl = (l & 7) ^ lr, swz = l15 & 7;
  f32x4 z4 = {0.f, 0.f, 0.f, 0.f};
  f32x4 acc[8][4];
  for (int i = 0; i < 8; ++i) for (int j = 0; j < 4; ++j) acc[i][j] = z4;

  stage8(Qb, Kb, smem, 0, 0, 512, w, lr, sl);
  asm volatile("s_waitcnt vmcnt(0)" ::: "memory");
  __builtin_amdgcn_s_barrier();
  __builtin_amdgcn_sched_barrier(0);

  for (int t = 0; t < 8; ++t) {
    int c = t & 1;
    if (t + 1 < 8) stage8(Qb, Kb, smem, c ^ 1, t + 1, 512, w, lr, sl);
    const bf16* At = smem + c * 32768;
    const bf16* Bt = At + 16384;
    __builtin_amdgcn_s_setprio(1);
    #pragma unroll
    for (int kk = 0; kk < 2; ++kk) {
      int ps = (kk * 4 + lg) ^ swz;
      bf16x8 a[8], b[4];
      #pragma unroll
      for (int i = 0; i < 8; ++i)
        a[i] = *(const bf16x8*)&At[(wm2 * 128 + i * 16 + l15) * 64 + ps * 8];
      #pragma unroll
      for (int j = 0; j < 4; ++j)
        b[j] = *(const bf16x8*)&Bt[(wn4 * 64 + j * 16 + l15) * 64 + ps * 8];
      #pragma unroll
      for (int i = 0; i < 8; ++i)
        #pragma unroll
        for (int j = 0; j < 4; ++j)
          acc[i][j] = __builtin_amdgcn_mfma_f32_16x16x32_bf16(a[i], b[j], acc[i][j], 0, 0, 0);
    }
    __builtin_amdgcn_s_setprio(0);
    asm volatile("s_waitcnt vmcnt(0)" ::: "memory");   // next buf staged (covered by compute)
    __builtin_amdgcn_s_barrier();
    __builtin_amdgcn_sched_barrier(0);
  }

  const float SCALE = 0.04419417382415922f;  // 1/sqrt(512)
  bf16* Sb = S + (size_t)batch * 1024 * 1024;
  #pragma unroll
  for (int i = 0; i < 8; ++i)
    #pragma unroll
    for (int j = 0; j < 4; ++j)
      #pragma unroll
      for (int r = 0; r < 4; ++r) {
        int row = tm * 256 + wm2 * 128 + i * 16 + lg * 4 + r;
        int col = tn * 256 + wn4 * 64 + j * 16 + l15;
        Sb[(size_t)row * 1024 + col] = __float2bfloat16(acc[i][j][r] * SCALE);
      }

  // optional softmax partials over this wave's 64-col slice (tn*4 + wn4)
  if (part != nullptr) {
    #pragma unroll
    for (int i = 0; i < 8; ++i)
      #pragma unroll
      for (int r = 0; r < 4; ++r) {
        float v0 = acc[i][0][r] * SCALE, v1 = acc[i][1][r] * SCALE;
        float v2 = acc[i][2][r] * SCALE, v3 = acc[i][3][r] * SCALE;
        float m = fmaxf(fmaxf(v0, v1), fmaxf(v2, v3));
        #pragma unroll
        for (int d = 1; d < 16; d <<= 1) m = fmaxf(m, __shfl_xor(m, d));
        float s = __expf(v0 - m) + __expf(v1 - m) + __expf(v2 - m) + __expf(v3 - m);
        #pragma unroll
        for (int d = 1; d < 16; d <<= 1) s += __shfl_xor(s, d);
        if (l15 == 0) {
          int grow = tm * 256 + wm2 * 128 + i * 16 + lg * 4 + r;
          float2 st; st.x = m; st.y = s;
          part[((size_t)batch * 1024 + grow) * 16 + tn * 4 + wn4] = st;
        }
      }
  }
}

// ---------------- combine 16 per-slice partials -> pstats (m, 1/sum) ----------------
__global__ __launch_bounds__(256) void combine_stats(const float2* __restrict__ part,
                                                     float2* __restrict__ pstats) {
  int row = blockIdx.x * 256 + threadIdx.x;
  const float2* p = part + (size_t)row * 16;
  float2 v[16];
  #pragma unroll
  for (int i = 0; i < 16; ++i) v[i] = p[i];
  float m = v[0].x;
  #pragma unroll
  for (int i = 1; i < 16; ++i) m = fmaxf(m, v[i].x);
  float s = 0.f;
  #pragma unroll
  for (int i = 0; i < 16; ++i) s += v[i].y * __expf(v[i].x - m);
  float2 st; st.x = m; st.y = 1.0f / s;
  pstats[row] = st;
}

// ---------------- fallback: row stats from S (round-10 path) ----------------
__global__ __launch_bounds__(256) void row_stats(const bf16* __restrict__ S, float2* __restrict__ pstats) {
  int l = threadIdx.x & 63;
  size_t row = (size_t)blockIdx.x * 4 + (threadIdx.x >> 6);
  const bf16* p = S + row * 1024 + l * 16;
  bf16x8 s0 = *(const bf16x8*)p;
  bf16x8 s1 = *(const bf16x8*)(p + 8);
  float f[16];
  #pragma unroll
  for (int i = 0; i < 8; ++i) { f[i] = b2f((unsigned short)s0[i]); f[8 + i] = b2f((unsigned short)s1[i]); }
  float m = f[0];
  #pragma unroll
  for (int i = 1; i < 16; ++i) m = fmaxf(m, f[i]);
  for (int d = 1; d < 64; d <<= 1) m = fmaxf(m, __shfl_xor(m, d));
  float sum = 0.f;
  #pragma unroll
  for (int i = 0; i < 16; ++i) sum += __expf(f[i] - m);
  for (int d = 1; d < 64; d <<= 1) sum += __shfl_xor(sum, d);
  if (l == 0) {
    float2 st; st.x = m; st.y = 1.0f / sum;
    pstats[row] = st;
  }
}

// ---------------- batched PV (A = exp(S-m)*rcp staged in-reg; B = Vt) ----------------
__global__ __launch_bounds__(512, 2) void pv_gemm(const bf16* __restrict__ S, const bf16* __restrict__ vt,
                                                  const float2* __restrict__ pstats,
                                                  bf16* __restrict__ y) {
  __shared__ bf16 smem[65536];         // 128 KiB: 2 bufs x (A 32K + B 32K)
  int tid = threadIdx.x;
  int bid = (blockIdx.x & 7) * 64 + (blockIdx.x >> 3);     // XCD swizzle (512 % 8 == 0)
  int batch = bid >> 3, bq = (bid >> 1) & 3, bd = bid & 1;
  const bf16* Pb = S + (size_t)batch * 1024 * 1024 + (size_t)bq * 256 * 1024;
  const bf16* Vb = vt + (size_t)batch * 512 * 1024 + (size_t)bd * 256 * 1024;
  int w = tid >> 6, l = tid & 63, l15 = l & 15, lg = l >> 4;
  int wm2 = w >> 2, wn4 = w & 3;
  int lr = l >> 3, sl = (l & 7) ^ lr, swz = l15 & 7;
  f32x4 z4 = {0.f, 0.f, 0.f, 0.f};
  f32x4 acc[8][4];
  for (int i = 0; i < 8; ++i) for (int j = 0; j < 4; ++j) acc[i][j] = z4;

  // per-thread A rows are iteration-invariant: preload (m, rcp)
  float m4[4], r4[4];
  #pragma unroll
  for (int p = 0; p < 4; ++p) {
    float2 st = pstats[(size_t)batch * 1024 + bq * 256 + p * 64 + w * 8 + lr];
    m4[p] = st.x; r4[p] = st.y;
  }

  bf16x8 areg[4];
  #define PV_ISSUE(tt, cc)                                                        \
    {                                                                             \
      _Pragma("unroll")                                                           \
      for (int p = 0; p < 4; ++p)                                                 \
        areg[p] = *(const bf16x8*)&Pb[(size_t)(p * 64 + w * 8 + lr) * 1024 +      \
                                      (tt) * 64 + sl * 8];                        \
      _Pragma("unroll")                                                           \
      for (int p = 0; p < 4; ++p)                                                 \
        gload_lds16(Vb + (size_t)(p * 64 + w * 8 + lr) * 1024 + (tt) * 64 + sl * 8, \
                    (char*)smem + (cc) * 65536 + 32768 + p * 8192 + w * 1024);    \
    }
  #define PV_WRITE_A(cc)                                                          \
    {                                                                             \
      _Pragma("unroll")                                                           \
      for (int p = 0; p < 4; ++p) {                                               \
        bf16x8 o;                                                                 \
        _Pragma("unroll")                                                         \
        for (int e = 0; e < 8; ++e) {                                             \
          float fv = b2f((unsigned short)areg[p][e]);                             \
          o[e] = (short)f2b(__expf(fv - m4[p]) * r4[p]);                          \
        }                                                                         \
        *(bf16x8*)((char*)smem + (cc) * 65536 + p * 8192 + w * 1024 + l * 16) = o; \
      }                                                                           \
    }

  PV_ISSUE(0, 0);
  asm volatile("s_waitcnt vmcnt(0)" ::: "memory");
  PV_WRITE_A(0);
  asm volatile("s_waitcnt lgkmcnt(0)" ::: "memory");
  __builtin_amdgcn_s_barrier();
  __builtin_amdgcn_sched_barrier(0);

  for (int t = 0; t < 16; ++t) {
    int c = t & 1;
    if (t + 1 < 16) PV_ISSUE(t + 1, c ^ 1);
    const bf16* At = smem + c * 32768;
    const bf16* Bt = At + 16384;
    __builtin_amdgcn_s_setprio(1);
    #pragma unroll
    for (int kk = 0; kk < 2; ++kk) {
      int ps = (kk * 4 + lg) ^ swz;
      bf16x8 a[8], b[4];
      #pragma unroll
      for (int i = 0; i < 8; ++i)
        a[i] = *(const bf16x8*)&At[(wm2 * 128 + i * 16 + l15) * 64 + ps * 8];
      #pragma unroll
      for (int j = 0; j < 4; ++j)
        b[j] = *(const bf16x8*)&Bt[(wn4 * 64 + j * 16 + l15) * 64 + ps * 8];
      #pragma unroll
      for (int i = 0; i < 8; ++i)
        #pragma unroll
        for (int j = 0; j < 4; ++j)
          acc[i][j] = __builtin_amdgcn_mfma_f32_16x16x32_bf16(a[i], b[j], acc[i][j], 0, 0, 0);
    }
    __builtin_amdgcn_s_setprio(0);
    asm volatile("s_waitcnt vmcnt(0)" ::: "memory");   // areg(t+1) arrived + B(t+1) landed
    if (t + 1 < 16) PV_WRITE_A(c ^ 1);
    asm volatile("s_waitcnt lgkmcnt(0)" ::: "memory");
    __builtin_amdgcn_s_barrier();
    __builtin_amdgcn_sched_barrier(0);
  }

  // epilogue: direct channels-last stores (16B runs per 8 lanes)
  int t2 = batch >> 3, h = batch & 7;
  #pragma unroll
  for (int i = 0; i < 8; ++i)
    #pragma unroll
    for (int j = 0; j < 4; ++j)
      #pragma unroll
      for (int r = 0; r < 4; ++r) {
        int win = bq * 256 + wm2 * 128 + i * 16 + lg * 4 + r;
        int dp = bd * 256 + wn4 * 64 + j * 16 + l15;
        int jj = dp & 7, pyix = dp >> 3;
        int gy = win >> 5, gx = win & 31;
        int Y = gy * 8 + (pyix >> 3), X = gx * 8 + (pyix & 7);
        y[(((size_t)t2 * 256 + Y) * 256 + X) * 64 + h * 8 + jj] = __float2bfloat16(acc[i][j][r]);
      }
}

// ---------------- final full-image conv + residual -> f32 out ----------------
__global__ __launch_bounds__(256) void out_conv(const bf16* __restrict__ yimg, const bf16* __restrict__ wot,
                                                const float* __restrict__ bo, float* __restrict__ out) {
  __shared__ bf16 yp[324 * 76];        // [py*18+px][ci pad76]
  int tid = threadIdx.x, bid = blockIdx.x;
  int t = bid >> 8, tile = bid & 255;
  int y0 = (tile >> 4) * 16, x0 = (tile & 15) * 16;
  const bf16* yb = yimg + (size_t)t * 256 * 256 * 64;

  for (int e = tid; e < 324 * 8; e += 256) {
    int seg = e & 7, pos = e >> 3;
    int ppx = pos % 18, ppy = pos / 18;
    int gy = y0 + ppy - 1, gx = x0 + ppx - 1;
    bf16x8 val = {0, 0, 0, 0, 0, 0, 0, 0};
    if ((unsigned)gy < 256u && (unsigned)gx < 256u)
      val = *(const bf16x8*)&yb[((size_t)gy * 256 + gx) * 64 + seg * 8];
    *(bf16x8*)&yp[pos * 76 + seg * 8] = val;
  }
  __syncthreads();

  int wv = tid >> 6, l = tid & 63, l15 = l & 15, lg = l >> 4;
  int wm = wv & 1, wn = wv >> 1;
  f32x4 z4 = {0.f, 0.f, 0.f, 0.f};
  f32x4 acc[2][8];
  for (int i = 0; i < 2; ++i) for (int j = 0; j < 8; ++j) acc[i][j] = z4;

  #pragma unroll
  for (int s9 = 0; s9 < 9; ++s9) {
    const int dy = s9 / 3, dx = s9 % 3;
    #pragma unroll
    for (int half = 0; half < 2; ++half) {
      bf16x8 a[2];
      #pragma unroll
      for (int mt = 0; mt < 2; ++mt)
        a[mt] = *(const bf16x8*)&wot[((size_t)s9 * 64 + wm * 32 + mt * 16 + l15) * 64 + half * 32 + lg * 8];
      #pragma unroll
      for (int nt = 0; nt < 8; ++nt) {
        int ty = wn * 8 + nt;
        bf16x8 b = *(const bf16x8*)&yp[((ty + dy) * 18 + l15 + dx) * 76 + half * 32 + lg * 8];
        #pragma unroll
        for (int mt = 0; mt < 2; ++mt)
          acc[mt][nt] = __builtin_amdgcn_mfma_f32_16x16x32_bf16(a[mt], b, acc[mt][nt], 0, 0, 0);
      }
    }
  }

  float* ob = out + (size_t)t * 64 * 65536;
  float bias[2][4];
  #pragma unroll
  for (int mt = 0; mt < 2; ++mt)
    #pragma unroll
    for (int r = 0; r < 4; ++r) bias[mt][r] = bo[wm * 32 + mt * 16 + lg * 4 + r];
  #pragma unroll
  for (int mt = 0; mt < 2; ++mt)
    #pragma unroll
    for (int nt = 0; nt < 8; ++nt) {
      int ty = wn * 8 + nt;
      #pragma unroll
      for (int r = 0; r < 4; ++r) {
        int co = wm * 32 + mt * 16 + lg * 4 + r;
        float res = b2f(*(const unsigned short*)&yp[((ty + 1) * 18 + l15 + 1) * 76 + co]);
        ob[(size_t)co * 65536 + (size_t)(y0 + ty) * 256 + x0 + l15] = res + acc[mt][nt][r] + bias[mt][r];
      }
    }
}

// ---------------- launcher ----------------
extern "C" void kernel_launch(void* const* d_in, const int* in_sizes, int n_in,
                              void* d_out, int out_size, void* d_ws, size_t ws_size,
                              hipStream_t stream) {
  const float* x  = (const float*)d_in[0];
  const float* Wq = (const float*)d_in[1];
  const float* bq = (const float*)d_in[2];
  const float* Wk = (const float*)d_in[3];
  const float* bk = (const float*)d_in[4];
  const float* Wv = (const float*)d_in[5];
  const float* bv = (const float*)d_in[6];
  const float* Wo = (const float*)d_in[7];
  const float* bo = (const float*)d_in[8];
  float* out = (float*)d_out;

  char* ws = (char*)d_ws;
  bf16* wt  = (bf16*)(ws + 0);
  bf16* wot = (bf16*)(ws + 110592);
  bf16* q   = (bf16*)(ws + 262144);              // reused as y_img after qk_gemm
  bf16* k   = (bf16*)(ws + 67371008);
  float2* pstats = (float2*)(ws + 67371008);     // overlaps k (dead after qk_gemm)
  bf16* S   = (bf16*)(ws + 134479872);
  bf16* vt  = (bf16*)(ws + 268697600);
  bf16* y   = (bf16*)(ws + 262144);              // channels-last [8][256][256][64]
  bf16* v   = S;                                 // v staged where S will go (dead before qk)
  const size_t PART_OFF = 335806464ull;
  const size_t PART_BYTES = 64ull * 1024 * 16 * sizeof(float2);   // 8 MiB
  bool fused_stats = (ws_size >= PART_OFF + PART_BYTES);
  float2* part = fused_stats ? (float2*)(ws + PART_OFF) : nullptr;

  prep_w<<<216, 256, 0, stream>>>(Wq, Wk, Wv, Wo, wt, wot);
  qkv_conv<<<4096, 256, 0, stream>>>(x, wt, bq, bk, bv, q, k, v);
  transpose_v<<<8192, 256, 0, stream>>>(v, vt);
  qk_gemm<<<1024, 512, 0, stream>>>(q, k, S, part);
  if (fused_stats)
    combine_stats<<<256, 256, 0, stream>>>(part, pstats);
  else
    row_stats<<<16384, 256, 0, stream>>>(S, pstats);
  pv_gemm<<<512, 512, 0, stream>>>(S, vt, pstats, y);
  out_conv<<<2048, 256, 0, stream>>>(y, wot, bo, out);
}

// Round 12
// 450.012 us; speedup vs baseline: 1.0697x; 1.0697x over previous
//
#include <hip/hip_runtime.h>
#include <hip/hip_bf16.h>
#include <stdint.h>

// Spatial local attention, MI355X bf16-MFMA implementation.
// Round 12: reverts (stats fusion out, qkv back to round-10 113us form) +
// qk_gemm ported to 16-phase ring-4 counted-vmcnt schedule (T3/T4):
// BK=32/phase, 4-slot LDS ring, stage t+3 at phase t, vmcnt(8) steady state.
//
// Workspace layout (bytes), total = 335,806,464 (~320.3 MiB):
//   [0        , 110592   ) Wqkv_t bf16 [9][192][32]
//   [110592   , 184320   ) Wo_t   bf16 [9][64][64]
//   [262144   , 67371008 ) q  bf16 [64][1024][512]   (reused as y_img bf16 [8][256][256][64] channels-last)
//   [67371008 , 134479872) k  bf16 [64][1024][512]   (first 512KB reused as pstats after qk_gemm)
//   [134479872, 268697600) S   bf16 [64][1024][1024] (raw scaled scores; exp applied in pv)
//   [268697600, 335806464) vt bf16 [64][512][1024]   (rows indexed by d' = pyix*8+jj)

using bf16 = __hip_bfloat16;
typedef short bf16x8 __attribute__((ext_vector_type(8)));
typedef float f32x4 __attribute__((ext_vector_type(4)));

#define AS1 __attribute__((address_space(1)))
#define AS3 __attribute__((address_space(3)))

__device__ __forceinline__ void gload_lds16(const void* g, void* l) {
  __builtin_amdgcn_global_load_lds((const AS1 unsigned int*)g, (AS3 unsigned int*)l, 16, 0, 0);
}
__device__ __forceinline__ float b2f(unsigned short u) {
  union { unsigned int i; float f; } x; x.i = ((unsigned)u) << 16; return x.f;
}
__device__ __forceinline__ unsigned short f2b(float f) {
  __hip_bfloat16 h = __float2bfloat16(f);
  return *reinterpret_cast<unsigned short*>(&h);
}

// ---------------- weight prep: f32 OIHW -> bf16 [step][co][ci] ----------------
__global__ __launch_bounds__(256) void prep_w(const float* __restrict__ Wq, const float* __restrict__ Wk,
                                              const float* __restrict__ Wv, const float* __restrict__ Wo,
                                              bf16* __restrict__ wt, bf16* __restrict__ wot) {
  int i = blockIdx.x * 256 + threadIdx.x;
  if (i < 9 * 192 * 32) {              // wt[s][co192][ci]
    int ci = i & 31, co192 = (i >> 5) % 192, s = i / 6144;
    int dy = s / 3, dx = s % 3;
    int proj = co192 >> 6, co = co192 & 63;
    const float* Ws = (proj == 0) ? Wq : ((proj == 1) ? Wk : Wv);
    wt[i] = __float2bfloat16(Ws[((co * 32 + ci) * 3 + dy) * 3 + dx]);
  }
  if (i < 9 * 64 * 64) {               // wot[s][co][ci]
    int ci = i & 63, co = (i >> 6) & 63, s = i >> 12;
    wot[i] = __float2bfloat16(Wo[((co * 64 + ci) * 3 + (s / 3)) * 3 + (s % 3)]);
  }
}

// ---------------- QKV windowed conv (round-10 exact: round-7 staging) ----------------
__global__ __launch_bounds__(256) void qkv_conv(const float* __restrict__ x, const bf16* __restrict__ wt,
                                                const float* __restrict__ bq, const float* __restrict__ bk,
                                                const float* __restrict__ bv,
                                                bf16* __restrict__ qout, bf16* __restrict__ kout,
                                                bf16* __restrict__ vout) {
  __shared__ bf16 smem[192 * 136];     // union: xp [2*100][40] (8000 el) | outl [192][136]
  bf16* xp = smem;
  int tid = threadIdx.x, bid = blockIdx.x;
  int t = bid >> 9, g = bid & 511;
  int gy = g >> 4, gx0 = (g & 15) * 2;

  unsigned int* xp32 = (unsigned int*)xp;
  for (int i = tid; i < 4000; i += 256) xp32[i] = 0u;
  __syncthreads();
  const float* xb = x + (size_t)t * 32 * 65536;
  #pragma unroll
  for (int it = 0; it < 16; ++it) {
    int e = tid + it * 256;
    int ix = e & 7, win = (e >> 3) & 1, iy = (e >> 4) & 7, ci = e >> 7;
    float val = xb[(size_t)ci * 65536 + (gy * 8 + iy) * 256 + (gx0 + win) * 8 + ix];
    xp[(win * 100 + (iy + 1) * 10 + (ix + 1)) * 40 + ci] = __float2bfloat16(val);
  }
  __syncthreads();

  int wv = tid >> 6, l = tid & 63, l15 = l & 15, lg = l >> 4;
  f32x4 z4 = {0.f, 0.f, 0.f, 0.f};
  f32x4 acc[3][8];
  for (int i = 0; i < 3; ++i) for (int j = 0; j < 8; ++j) acc[i][j] = z4;

  #pragma unroll
  for (int s = 0; s < 9; ++s) {
    const int dy = s / 3, dx = s % 3;
    bf16x8 a[3];
    #pragma unroll
    for (int mt = 0; mt < 3; ++mt)
      a[mt] = *(const bf16x8*)&wt[((size_t)s * 192 + wv * 48 + mt * 16 + l15) * 32 + lg * 8];
    #pragma unroll
    for (int nt = 0; nt < 8; ++nt) {
      int n = nt * 16 + l15;
      int win = n >> 6, px = n & 63;
      int iy = px >> 3, ix = px & 7;
      bf16x8 b = *(const bf16x8*)&xp[(win * 100 + (iy + dy) * 10 + (ix + dx)) * 40 + lg * 8];
      #pragma unroll
      for (int mt = 0; mt < 3; ++mt)
        acc[mt][nt] = __builtin_amdgcn_mfma_f32_16x16x32_bf16(a[mt], b, acc[mt][nt], 0, 0, 0);
    }
  }

  // epilogue pass 1: acc+bias -> outl[co192][n], stride 136
  __syncthreads();
  bf16* outl = smem;
  #pragma unroll
  for (int mt = 0; mt < 3; ++mt) {
    int c0 = wv * 48 + mt * 16 + lg * 4;
    int proj = c0 >> 6;
    const float* bptr = (proj == 0) ? bq : ((proj == 1) ? bk : bv);
    float bias[4];
    #pragma unroll
    for (int r = 0; r < 4; ++r) bias[r] = bptr[(c0 + r) & 63];
    #pragma unroll
    for (int nt = 0; nt < 8; ++nt) {
      int n = nt * 16 + l15;
      #pragma unroll
      for (int r = 0; r < 4; ++r)
        outl[(c0 + r) * 136 + n] = __float2bfloat16(acc[mt][nt][r] + bias[r]);
    }
  }
  __syncthreads();

  // epilogue pass 2: coalesced 16B stores. chunk c: [win(1)|head(3)|d8(6)] per proj.
  #pragma unroll
  for (int proj = 0; proj < 3; ++proj) {
    bf16* dst = (proj == 0) ? qout : ((proj == 1) ? kout : vout);
    #pragma unroll
    for (int pass = 0; pass < 4; ++pass) {
      int c = pass * 256 + tid;
      int d8 = c & 63, head = (c >> 6) & 7, wn2 = c >> 9;
      int jj = d8 >> 3, px0 = (d8 & 7) * 8;
      bf16x8 val = *(const bf16x8*)&outl[(proj * 64 + head * 8 + jj) * 136 + wn2 * 64 + px0];
      size_t gwin = (size_t)gy * 32 + gx0 + wn2;
      *(bf16x8*)&dst[((size_t)(t * 8 + head) * 1024 + gwin) * 512 + d8 * 8] = val;
    }
  }
}

// ---------------- V transpose + d-permute: [bh][win][d=jj*64+pyix] -> [bh][d'=pyix*8+jj][win] ----------------
__global__ __launch_bounds__(256) void transpose_v(const bf16* __restrict__ v, bf16* __restrict__ vt) {
  __shared__ bf16 tl[64 * 72];         // [d_local][win pad72]
  int tid = threadIdx.x, bid = blockIdx.x;
  int bh = bid >> 7, wtile = (bid >> 3) & 15, dtile = bid & 7;   // dtile == jj
  int w0 = wtile * 64, d0 = dtile * 64;
  const bf16* vb = v + ((size_t)bh * 1024 + w0) * 512 + d0;
  int win_l = tid >> 2, dseg = (tid & 3) * 16;
  bf16x8 x0 = *(const bf16x8*)&vb[(size_t)win_l * 512 + dseg];
  bf16x8 x1 = *(const bf16x8*)&vb[(size_t)win_l * 512 + dseg + 8];
  #pragma unroll
  for (int j = 0; j < 8; ++j) {
    *(short*)&tl[(dseg + j) * 72 + win_l] = x0[j];
    *(short*)&tl[(dseg + 8 + j) * 72 + win_l] = x1[j];
  }
  __syncthreads();
  int d_l = tid >> 2, wseg = (tid & 3) * 16;   // d_l == pyix
  bf16x8 y0 = *(const bf16x8*)&tl[d_l * 72 + wseg];
  bf16x8 y1 = *(const bf16x8*)&tl[d_l * 72 + wseg + 8];
  bf16* vtb = vt + ((size_t)bh * 512 + d_l * 8 + dtile) * 1024 + w0 + wseg;
  *(bf16x8*)&vtb[0] = y0;
  *(bf16x8*)&vtb[8] = y1;
}

// ---------------- batched QK^T -> S bf16: 16-phase ring-4 counted-vmcnt ----------------
// 256x256 tile, 8 waves, BK=32 per phase, 4-slot LDS ring (slot = 32KB: A 16KB + B 16KB).
// Phase t: vmcnt(8) -> barrier -> ds_read frags(slot t&3) -> stage tile t+3 (slot (t+3)&3,
// = slot freed by phase t-1's lgkmcnt+barrier) -> lgkmcnt(0) -> 32 MFMA.
// Swizzle (BK=32): phys 8-elem slot = logical ^ (row&3); staged via pre-swizzled source.
__global__ __launch_bounds__(512, 2) void qk_gemm(const bf16* __restrict__ q, const bf16* __restrict__ k,
                                                  bf16* __restrict__ S) {
  __shared__ bf16 smem[65536];         // 128 KiB: 4 slots x 16384 elems
  int tid = threadIdx.x;
  int bid = (blockIdx.x & 7) * 128 + (blockIdx.x >> 3);    // XCD swizzle (1024 % 8 == 0)
  int batch = bid >> 4, tm = (bid >> 2) & 3, tn = bid & 3;
  const bf16* Qb = q + (size_t)batch * 1024 * 512 + (size_t)tm * 256 * 512;
  const bf16* Kb = k + (size_t)batch * 1024 * 512 + (size_t)tn * 256 * 512;
  int w = tid >> 6, l = tid & 63, l15 = l & 15, lg = l >> 4;
  int wm2 = w >> 2, wn4 = w & 3;
  int srow_lo = l >> 2;                 // 0..15: within-wave staged row
  int ssl = (l & 3) ^ (srow_lo & 3);    // pre-swizzled source 8-elem slot (row&3 == srow_lo&3)
  int swz2 = l15 & 3;                   // read-side key (frag row&3 == l15&3)
  f32x4 z4 = {0.f, 0.f, 0.f, 0.f};
  f32x4 acc[8][4];
  for (int i = 0; i < 8; ++i) for (int j = 0; j < 4; ++j) acc[i][j] = z4;

  // stage K-tile T (32-wide) into ring slot T&3: per thread 2xA + 2xB 16B loads
  #define QK_STAGE(T)                                                            \
    {                                                                            \
      char* sbase = (char*)smem + ((T) & 3) * 32768;                             \
      _Pragma("unroll")                                                          \
      for (int p = 0; p < 2; ++p) {                                              \
        int row = p * 128 + w * 16 + srow_lo;                                    \
        gload_lds16(Qb + (size_t)row * 512 + (T) * 32 + ssl * 8,                 \
                    sbase + p * 8192 + w * 1024);                                \
        gload_lds16(Kb + (size_t)row * 512 + (T) * 32 + ssl * 8,                 \
                    sbase + 16384 + p * 8192 + w * 1024);                        \
      }                                                                          \
    }

  QK_STAGE(0); QK_STAGE(1); QK_STAGE(2);   // prologue: 12 loads in flight

  #pragma unroll
  for (int t = 0; t < 16; ++t) {
    // tile t landed; allow tiles t+1, t+2 (8 loads) in flight
    if (t <= 13)      asm volatile("s_waitcnt vmcnt(8)" ::: "memory");
    else if (t == 14) asm volatile("s_waitcnt vmcnt(4)" ::: "memory");
    else              asm volatile("s_waitcnt vmcnt(0)" ::: "memory");
    __builtin_amdgcn_s_barrier();
    __builtin_amdgcn_sched_barrier(0);

    const int se = (t & 3) * 16384;      // slot base (elems)
    bf16x8 a[8], b[4];
    #pragma unroll
    for (int i = 0; i < 8; ++i)
      a[i] = *(const bf16x8*)&smem[se + (wm2 * 128 + i * 16 + l15) * 32 + ((lg ^ swz2) * 8)];
    #pragma unroll
    for (int j = 0; j < 4; ++j)
      b[j] = *(const bf16x8*)&smem[se + 8192 + (wn4 * 64 + j * 16 + l15) * 32 + ((lg ^ swz2) * 8)];

    if (t <= 12) QK_STAGE(t + 3);        // into slot (t-1)&3, freed by prev phase

    asm volatile("s_waitcnt lgkmcnt(0)" ::: "memory");
    __builtin_amdgcn_sched_barrier(0);
    __builtin_amdgcn_s_setprio(1);
    #pragma unroll
    for (int i = 0; i < 8; ++i)
      #pragma unroll
      for (int j = 0; j < 4; ++j)
        acc[i][j] = __builtin_amdgcn_mfma_f32_16x16x32_bf16(a[i], b[j], acc[i][j], 0, 0, 0);
    __builtin_amdgcn_s_setprio(0);
  }
  #undef QK_STAGE

  const float SCALE = 0.04419417382415922f;  // 1/sqrt(512)
  bf16* Sb = S + (size_t)batch * 1024 * 1024;
  #pragma unroll
  for (int i = 0; i < 8; ++i)
    #pragma unroll
    for (int j = 0; j < 4; ++j)
      #pragma unroll
      for (int r = 0; r < 4; ++r) {
        int row = tm * 256 + wm2 * 128 + i * 16 + lg * 4 + r;
        int col = tn * 256 + wn4 * 64 + j * 16 + l15;
        Sb[(size_t)row * 1024 + col] = __float2bfloat16(acc[i][j][r] * SCALE);
      }
}

// ---------------- row stats: per row m = max, rcp = 1/sum(exp(s-m)) ----------------
__global__ __launch_bounds__(256) void row_stats(const bf16* __restrict__ S, float2* __restrict__ pstats) {
  int l = threadIdx.x & 63;
  size_t row = (size_t)blockIdx.x * 4 + (threadIdx.x >> 6);
  const bf16* p = S + row * 1024 + l * 16;
  bf16x8 s0 = *(const bf16x8*)p;
  bf16x8 s1 = *(const bf16x8*)(p + 8);
  float f[16];
  #pragma unroll
  for (int i = 0; i < 8; ++i) { f[i] = b2f((unsigned short)s0[i]); f[8 + i] = b2f((unsigned short)s1[i]); }
  float m = f[0];
  #pragma unroll
  for (int i = 1; i < 16; ++i) m = fmaxf(m, f[i]);
  for (int d = 1; d < 64; d <<= 1) m = fmaxf(m, __shfl_xor(m, d));
  float sum = 0.f;
  #pragma unroll
  for (int i = 0; i < 16; ++i) sum += __expf(f[i] - m);
  for (int d = 1; d < 64; d <<= 1) sum += __shfl_xor(sum, d);
  if (l == 0) {
    float2 st; st.x = m; st.y = 1.0f / sum;
    pstats[row] = st;
  }
}

// ---------------- batched PV (A = exp(S-m)*rcp staged in-reg; B = Vt) ----------------
__global__ __launch_bounds__(512, 2) void pv_gemm(const bf16* __restrict__ S, const bf16* __restrict__ vt,
                                                  const float2* __restrict__ pstats,
                                                  bf16* __restrict__ y) {
  __shared__ bf16 smem[65536];         // 128 KiB: 2 bufs x (A 32K + B 32K)
  int tid = threadIdx.x;
  int bid = (blockIdx.x & 7) * 64 + (blockIdx.x >> 3);     // XCD swizzle (512 % 8 == 0)
  int batch = bid >> 3, bq = (bid >> 1) & 3, bd = bid & 1;
  const bf16* Pb = S + (size_t)batch * 1024 * 1024 + (size_t)bq * 256 * 1024;
  const bf16* Vb = vt + (size_t)batch * 512 * 1024 + (size_t)bd * 256 * 1024;
  int w = tid >> 6, l = tid & 63, l15 = l & 15, lg = l >> 4;
  int wm2 = w >> 2, wn4 = w & 3;
  int lr = l >> 3, sl = (l & 7) ^ lr, swz = l15 & 7;
  f32x4 z4 = {0.f, 0.f, 0.f, 0.f};
  f32x4 acc[8][4];
  for (int i = 0; i < 8; ++i) for (int j = 0; j < 4; ++j) acc[i][j] = z4;

  // per-thread A rows are iteration-invariant: preload (m, rcp)
  float m4[4], r4[4];
  #pragma unroll
  for (int p = 0; p < 4; ++p) {
    float2 st = pstats[(size_t)batch * 1024 + bq * 256 + p * 64 + w * 8 + lr];
    m4[p] = st.x; r4[p] = st.y;
  }

  bf16x8 areg[4];
  #define PV_ISSUE(tt, cc)                                                        \
    {                                                                             \
      _Pragma("unroll")                                                           \
      for (int p = 0; p < 4; ++p)                                                 \
        areg[p] = *(const bf16x8*)&Pb[(size_t)(p * 64 + w * 8 + lr) * 1024 +      \
                                      (tt) * 64 + sl * 8];                        \
      _Pragma("unroll")                                                           \
      for (int p = 0; p < 4; ++p)                                                 \
        gload_lds16(Vb + (size_t)(p * 64 + w * 8 + lr) * 1024 + (tt) * 64 + sl * 8, \
                    (char*)smem + (cc) * 65536 + 32768 + p * 8192 + w * 1024);    \
    }
  #define PV_WRITE_A(cc)                                                          \
    {                                                                             \
      _Pragma("unroll")                                                           \
      for (int p = 0; p < 4; ++p) {                                               \
        bf16x8 o;                                                                 \
        _Pragma("unroll")                                                         \
        for (int e = 0; e < 8; ++e) {                                             \
          float fv = b2f((unsigned short)areg[p][e]);                             \
          o[e] = (short)f2b(__expf(fv - m4[p]) * r4[p]);                          \
        }                                                                         \
        *(bf16x8*)((char*)smem + (cc) * 65536 + p * 8192 + w * 1024 + l * 16) = o; \
      }                                                                           \
    }

  PV_ISSUE(0, 0);
  asm volatile("s_waitcnt vmcnt(0)" ::: "memory");
  PV_WRITE_A(0);
  asm volatile("s_waitcnt lgkmcnt(0)" ::: "memory");
  __builtin_amdgcn_s_barrier();
  __builtin_amdgcn_sched_barrier(0);

  for (int t = 0; t < 16; ++t) {
    int c = t & 1;
    if (t + 1 < 16) PV_ISSUE(t + 1, c ^ 1);
    const bf16* At = smem + c * 32768;
    const bf16* Bt = At + 16384;
    __builtin_amdgcn_s_setprio(1);
    #pragma unroll
    for (int kk = 0; kk < 2; ++kk) {
      int ps = (kk * 4 + lg) ^ swz;
      bf16x8 a[8], b[4];
      #pragma unroll
      for (int i = 0; i < 8; ++i)
        a[i] = *(const bf16x8*)&At[(wm2 * 128 + i * 16 + l15) * 64 + ps * 8];
      #pragma unroll
      for (int j = 0; j < 4; ++j)
        b[j] = *(const bf16x8*)&Bt[(wn4 * 64 + j * 16 + l15) * 64 + ps * 8];
      #pragma unroll
      for (int i = 0; i < 8; ++i)
        #pragma unroll
        for (int j = 0; j < 4; ++j)
          acc[i][j] = __builtin_amdgcn_mfma_f32_16x16x32_bf16(a[i], b[j], acc[i][j], 0, 0, 0);
    }
    __builtin_amdgcn_s_setprio(0);
    asm volatile("s_waitcnt vmcnt(0)" ::: "memory");   // areg(t+1) arrived + B(t+1) landed
    if (t + 1 < 16) PV_WRITE_A(c ^ 1);
    asm volatile("s_waitcnt lgkmcnt(0)" ::: "memory");
    __builtin_amdgcn_s_barrier();
    __builtin_amdgcn_sched_barrier(0);
  }

  // epilogue: direct channels-last stores (16B runs per 8 lanes)
  int t2 = batch >> 3, h = batch & 7;
  #pragma unroll
  for (int i = 0; i < 8; ++i)
    #pragma unroll
    for (int j = 0; j < 4; ++j)
      #pragma unroll
      for (int r = 0; r < 4; ++r) {
        int win = bq * 256 + wm2 * 128 + i * 16 + lg * 4 + r;
        int dp = bd * 256 + wn4 * 64 + j * 16 + l15;
        int jj = dp & 7, pyix = dp >> 3;
        int gy = win >> 5, gx = win & 31;
        int Y = gy * 8 + (pyix >> 3), X = gx * 8 + (pyix & 7);
        y[(((size_t)t2 * 256 + Y) * 256 + X) * 64 + h * 8 + jj] = __float2bfloat16(acc[i][j][r]);
      }
}

// ---------------- final full-image conv + residual -> f32 out ----------------
__global__ __launch_bounds__(256) void out_conv(const bf16* __restrict__ yimg, const bf16* __restrict__ wot,
                                                const float* __restrict__ bo, float* __restrict__ out) {
  __shared__ bf16 yp[324 * 76];        // [py*18+px][ci pad76]
  int tid = threadIdx.x, bid = blockIdx.x;
  int t = bid >> 8, tile = bid & 255;
  int y0 = (tile >> 4) * 16, x0 = (tile & 15) * 16;
  const bf16* yb = yimg + (size_t)t * 256 * 256 * 64;

  for (int e = tid; e < 324 * 8; e += 256) {
    int seg = e & 7, pos = e >> 3;
    int ppx = pos % 18, ppy = pos / 18;
    int gy = y0 + ppy - 1, gx = x0 + ppx - 1;
    bf16x8 val = {0, 0, 0, 0, 0, 0, 0, 0};
    if ((unsigned)gy < 256u && (unsigned)gx < 256u)
      val = *(const bf16x8*)&yb[((size_t)gy * 256 + gx) * 64 + seg * 8];
    *(bf16x8*)&yp[pos * 76 + seg * 8] = val;
  }
  __syncthreads();

  int wv = tid >> 6, l = tid & 63, l15 = l & 15, lg = l >> 4;
  int wm = wv & 1, wn = wv >> 1;
  f32x4 z4 = {0.f, 0.f, 0.f, 0.f};
  f32x4 acc[2][8];
  for (int i = 0; i < 2; ++i) for (int j = 0; j < 8; ++j) acc[i][j] = z4;

  #pragma unroll
  for (int s9 = 0; s9 < 9; ++s9) {
    const int dy = s9 / 3, dx = s9 % 3;
    #pragma unroll
    for (int half = 0; half < 2; ++half) {
      bf16x8 a[2];
      #pragma unroll
      for (int mt = 0; mt < 2; ++mt)
        a[mt] = *(const bf16x8*)&wot[((size_t)s9 * 64 + wm * 32 + mt * 16 + l15) * 64 + half * 32 + lg * 8];
      #pragma unroll
      for (int nt = 0; nt < 8; ++nt) {
        int ty = wn * 8 + nt;
        bf16x8 b = *(const bf16x8*)&yp[((ty + dy) * 18 + l15 + dx) * 76 + half * 32 + lg * 8];
        #pragma unroll
        for (int mt = 0; mt < 2; ++mt)
          acc[mt][nt] = __builtin_amdgcn_mfma_f32_16x16x32_bf16(a[mt], b, acc[mt][nt], 0, 0, 0);
      }
    }
  }

  float* ob = out + (size_t)t * 64 * 65536;
  float bias[2][4];
  #pragma unroll
  for (int mt = 0; mt < 2; ++mt)
    #pragma unroll
    for (int r = 0; r < 4; ++r) bias[mt][r] = bo[wm * 32 + mt * 16 + lg * 4 + r];
  #pragma unroll
  for (int mt = 0; mt < 2; ++mt)
    #pragma unroll
    for (int nt = 0; nt < 8; ++nt) {
      int ty = wn * 8 + nt;
      #pragma unroll
      for (int r = 0; r < 4; ++r) {
        int co = wm * 32 + mt * 16 + lg * 4 + r;
        float res = b2f(*(const unsigned short*)&yp[((ty + 1) * 18 + l15 + 1) * 76 + co]);
        ob[(size_t)co * 65536 + (size_t)(y0 + ty) * 256 + x0 + l15] = res + acc[mt][nt][r] + bias[mt][r];
      }
    }
}

// ---------------- launcher ----------------
extern "C" void kernel_launch(void* const* d_in, const int* in_sizes, int n_in,
                              void* d_out, int out_size, void* d_ws, size_t ws_size,
                              hipStream_t stream) {
  const float* x  = (const float*)d_in[0];
  const float* Wq = (const float*)d_in[1];
  const float* bq = (const float*)d_in[2];
  const float* Wk = (const float*)d_in[3];
  const float* bk = (const float*)d_in[4];
  const float* Wv = (const float*)d_in[5];
  const float* bv = (const float*)d_in[6];
  const float* Wo = (const float*)d_in[7];
  const float* bo = (const float*)d_in[8];
  float* out = (float*)d_out;

  char* ws = (char*)d_ws;
  bf16* wt  = (bf16*)(ws + 0);
  bf16* wot = (bf16*)(ws + 110592);
  bf16* q   = (bf16*)(ws + 262144);              // reused as y_img after qk_gemm
  bf16* k   = (bf16*)(ws + 67371008);
  float2* pstats = (float2*)(ws + 67371008);     // overlaps k (dead after qk_gemm)
  bf16* S   = (bf16*)(ws + 134479872);
  bf16* vt  = (bf16*)(ws + 268697600);
  bf16* y   = (bf16*)(ws + 262144);              // channels-last [8][256][256][64]
  bf16* v   = S;                                 // v staged where S will go (dead before qk)
  // requires ws_size >= 335,806,464 bytes

  prep_w<<<216, 256, 0, stream>>>(Wq, Wk, Wv, Wo, wt, wot);
  qkv_conv<<<4096, 256, 0, stream>>>(x, wt, bq, bk, bv, q, k, v);
  transpose_v<<<8192, 256, 0, stream>>>(v, vt);
  qk_gemm<<<1024, 512, 0, stream>>>(q, k, S);
  row_stats<<<16384, 256, 0, stream>>>(S, pstats);
  pv_gemm<<<512, 512, 0, stream>>>(S, vt, pstats, y);
  out_conv<<<2048, 256, 0, stream>>>(y, wot, bo, out);
}

// Round 13
// 434.773 us; speedup vs baseline: 1.1072x; 1.0350x over previous
//
#include <hip/hip_runtime.h>
#include <hip/hip_bf16.h>
#include <stdint.h>

// Spatial local attention, MI355X bf16-MFMA implementation.
// Round 13: q/k stored in permuted feature order d'' = pyix*8 + jj (QK^T invariant;
// matches V's d'). qkv_conv epilogue = direct 8B coalesced stores (no LDS restage,
// LDS 52->16KB). transpose_v = plain transpose. qk_gemm reverted to proven 2-phase
// BK=64 (round-10). out_conv gets __launch_bounds__(256,4).
//
// Workspace layout (bytes), total = 335,806,464 (~320.3 MiB):
//   [0        , 110592   ) Wqkv_t bf16 [9][192][32]
//   [110592   , 184320   ) Wo_t   bf16 [9][64][64]
//   [262144   , 67371008 ) q  bf16 [64][1024][512]   (d''-ordered; reused as y_img)
//   [67371008 , 134479872) k  bf16 [64][1024][512]   (d''-ordered; pstats overlays)
//   [134479872, 268697600) S   bf16 [64][1024][1024] (raw scaled scores)
//   [268697600, 335806464) vt bf16 [64][512][1024]   (rows = d' = pyix*8+jj)

using bf16 = __hip_bfloat16;
typedef short bf16x8 __attribute__((ext_vector_type(8)));
typedef short bf16x4 __attribute__((ext_vector_type(4)));
typedef float f32x4 __attribute__((ext_vector_type(4)));

#define AS1 __attribute__((address_space(1)))
#define AS3 __attribute__((address_space(3)))

__device__ __forceinline__ void gload_lds16(const void* g, void* l) {
  __builtin_amdgcn_global_load_lds((const AS1 unsigned int*)g, (AS3 unsigned int*)l, 16, 0, 0);
}
__device__ __forceinline__ float b2f(unsigned short u) {
  union { unsigned int i; float f; } x; x.i = ((unsigned)u) << 16; return x.f;
}
__device__ __forceinline__ unsigned short f2b(float f) {
  __hip_bfloat16 h = __float2bfloat16(f);
  return *reinterpret_cast<unsigned short*>(&h);
}

// ---------------- weight prep: f32 OIHW -> bf16 [step][co][ci] ----------------
__global__ __launch_bounds__(256) void prep_w(const float* __restrict__ Wq, const float* __restrict__ Wk,
                                              const float* __restrict__ Wv, const float* __restrict__ Wo,
                                              bf16* __restrict__ wt, bf16* __restrict__ wot) {
  int i = blockIdx.x * 256 + threadIdx.x;
  if (i < 9 * 192 * 32) {              // wt[s][co192][ci]
    int ci = i & 31, co192 = (i >> 5) % 192, s = i / 6144;
    int dy = s / 3, dx = s % 3;
    int proj = co192 >> 6, co = co192 & 63;
    const float* Ws = (proj == 0) ? Wq : ((proj == 1) ? Wk : Wv);
    wt[i] = __float2bfloat16(Ws[((co * 32 + ci) * 3 + dy) * 3 + dx]);
  }
  if (i < 9 * 64 * 64) {               // wot[s][co][ci]
    int ci = i & 63, co = (i >> 6) & 63, s = i >> 12;
    wot[i] = __float2bfloat16(Wo[((co * 64 + ci) * 3 + (s / 3)) * 3 + (s % 3)]);
  }
}

// ---------------- QKV windowed conv: direct d''-ordered stores ----------------
// block: 2 windows (128 px), M=192 (q|k|v x 64co), K = 9 steps x 32ci. 4 waves split M.
// q/k/v element (bh, gwin, d''=pyix*8+jj). Thread's 4 acc rows = 4 consecutive d''.
__global__ __launch_bounds__(256) void qkv_conv(const float* __restrict__ x, const bf16* __restrict__ wt,
                                                const float* __restrict__ bq, const float* __restrict__ bk,
                                                const float* __restrict__ bv,
                                                bf16* __restrict__ qout, bf16* __restrict__ kout,
                                                bf16* __restrict__ vout) {
  __shared__ bf16 xp[8000];            // [win][py*10+px][ci pad40], 16 KB
  int tid = threadIdx.x, bid = blockIdx.x;
  int t = bid >> 9, g = bid & 511;
  int gy = g >> 4, gx0 = (g & 15) * 2;

  unsigned int* xp32 = (unsigned int*)xp;
  for (int i = tid; i < 4000; i += 256) xp32[i] = 0u;
  __syncthreads();
  const float* xb = x + (size_t)t * 32 * 65536;
  #pragma unroll
  for (int it = 0; it < 16; ++it) {
    int e = tid + it * 256;
    int ix = e & 7, win = (e >> 3) & 1, iy = (e >> 4) & 7, ci = e >> 7;
    float val = xb[(size_t)ci * 65536 + (gy * 8 + iy) * 256 + (gx0 + win) * 8 + ix];
    xp[(win * 100 + (iy + 1) * 10 + (ix + 1)) * 40 + ci] = __float2bfloat16(val);
  }
  __syncthreads();

  int wv = tid >> 6, l = tid & 63, l15 = l & 15, lg = l >> 4;
  f32x4 z4 = {0.f, 0.f, 0.f, 0.f};
  f32x4 acc[3][8];
  for (int i = 0; i < 3; ++i) for (int j = 0; j < 8; ++j) acc[i][j] = z4;

  #pragma unroll
  for (int s = 0; s < 9; ++s) {
    const int dy = s / 3, dx = s % 3;
    bf16x8 a[3];
    #pragma unroll
    for (int mt = 0; mt < 3; ++mt)
      a[mt] = *(const bf16x8*)&wt[((size_t)s * 192 + wv * 48 + mt * 16 + l15) * 32 + lg * 8];
    #pragma unroll
    for (int nt = 0; nt < 8; ++nt) {
      int n = nt * 16 + l15;
      int win = n >> 6, px = n & 63;
      int iy = px >> 3, ix = px & 7;
      bf16x8 b = *(const bf16x8*)&xp[(win * 100 + (iy + dy) * 10 + (ix + dx)) * 40 + lg * 8];
      #pragma unroll
      for (int mt = 0; mt < 3; ++mt)
        acc[mt][nt] = __builtin_amdgcn_mfma_f32_16x16x32_bf16(a[mt], b, acc[mt][nt], 0, 0, 0);
    }
  }

  // epilogue: direct 8B stores. co = wv*48+mt*16+lg*4+r -> head = co0>>3 const,
  // jj = jj0+r (jj0 in {0,4}) -> d'' = pyix*8 + jj0 + r, 4 consecutive.
  #pragma unroll
  for (int mt = 0; mt < 3; ++mt) {
    int c0 = wv * 48 + mt * 16 + lg * 4;
    int proj = c0 >> 6;
    int co0 = c0 & 63;
    int head = co0 >> 3, jj0 = co0 & 7;
    const float* bptr = (proj == 0) ? bq : ((proj == 1) ? bk : bv);
    bf16* dst = (proj == 0) ? qout : ((proj == 1) ? kout : vout);
    float bias[4];
    #pragma unroll
    for (int r = 0; r < 4; ++r) bias[r] = bptr[co0 + r];
    size_t bh = (size_t)(t * 8 + head);
    #pragma unroll
    for (int nt = 0; nt < 8; ++nt) {
      int n = nt * 16 + l15;
      int win2 = n >> 6, pyix = n & 63;
      size_t gwin = (size_t)gy * 32 + gx0 + win2;
      bf16x4 pack;
      #pragma unroll
      for (int r = 0; r < 4; ++r) pack[r] = (short)f2b(acc[mt][nt][r] + bias[r]);
      *(bf16x4*)&dst[(bh * 1024 + gwin) * 512 + pyix * 8 + jj0] = pack;
    }
  }
}

// ---------------- V transpose (plain): [bh][win][d''] -> [bh][d''][win] ----------------
__global__ __launch_bounds__(256) void transpose_v(const bf16* __restrict__ v, bf16* __restrict__ vt) {
  __shared__ bf16 tl[64 * 72];         // [d_local][win pad72]
  int tid = threadIdx.x, bid = blockIdx.x;
  int bh = bid >> 7, wtile = (bid >> 3) & 15, dtile = bid & 7;
  int w0 = wtile * 64, d0 = dtile * 64;
  const bf16* vb = v + ((size_t)bh * 1024 + w0) * 512 + d0;
  int win_l = tid >> 2, dseg = (tid & 3) * 16;
  bf16x8 x0 = *(const bf16x8*)&vb[(size_t)win_l * 512 + dseg];
  bf16x8 x1 = *(const bf16x8*)&vb[(size_t)win_l * 512 + dseg + 8];
  #pragma unroll
  for (int j = 0; j < 8; ++j) {
    *(short*)&tl[(dseg + j) * 72 + win_l] = x0[j];
    *(short*)&tl[(dseg + 8 + j) * 72 + win_l] = x1[j];
  }
  __syncthreads();
  int d_l = tid >> 2, wseg = (tid & 3) * 16;
  bf16x8 y0 = *(const bf16x8*)&tl[d_l * 72 + wseg];
  bf16x8 y1 = *(const bf16x8*)&tl[d_l * 72 + wseg + 8];
  bf16* vtb = vt + ((size_t)bh * 512 + d0 + d_l) * 1024 + w0 + wseg;
  *(bf16x8*)&vtb[0] = y0;
  *(bf16x8*)&vtb[8] = y1;
}

// ---- shared 256x256 GEMM machinery: 8 waves, BK=64, dbuf, XOR slot swizzle ----
__device__ __forceinline__ void stage8(const bf16* __restrict__ Ab, const bf16* __restrict__ Bb,
                                       bf16* smem, int c, int t, int sk,
                                       int w, int lr, int sl) {
  #pragma unroll
  for (int p = 0; p < 4; ++p) {
    int row = p * 64 + w * 8 + lr;
    gload_lds16(Ab + (size_t)row * sk + t * 64 + sl * 8,
                (char*)smem + c * 65536 + p * 8192 + w * 1024);
    gload_lds16(Bb + (size_t)row * sk + t * 64 + sl * 8,
                (char*)smem + c * 65536 + 32768 + p * 8192 + w * 1024);
  }
}

// ---------------- batched QK^T -> S bf16 (scaled), 256x256 tile, 2-phase BK=64 ----------------
__global__ __launch_bounds__(512, 2) void qk_gemm(const bf16* __restrict__ q, const bf16* __restrict__ k,
                                                  bf16* __restrict__ S) {
  __shared__ bf16 smem[65536];         // 128 KiB: 2 bufs x (A 32K + B 32K)
  int tid = threadIdx.x;
  int bid = (blockIdx.x & 7) * 128 + (blockIdx.x >> 3);    // XCD swizzle (1024 % 8 == 0)
  int batch = bid >> 4, tm = (bid >> 2) & 3, tn = bid & 3;
  const bf16* Qb = q + (size_t)batch * 1024 * 512 + (size_t)tm * 256 * 512;
  const bf16* Kb = k + (size_t)batch * 1024 * 512 + (size_t)tn * 256 * 512;
  int w = tid >> 6, l = tid & 63, l15 = l & 15, lg = l >> 4;
  int wm2 = w >> 2, wn4 = w & 3;
  int lr = l >> 3, sl = (l & 7) ^ lr, swz = l15 & 7;
  f32x4 z4 = {0.f, 0.f, 0.f, 0.f};
  f32x4 acc[8][4];
  for (int i = 0; i < 8; ++i) for (int j = 0; j < 4; ++j) acc[i][j] = z4;

  stage8(Qb, Kb, smem, 0, 0, 512, w, lr, sl);
  asm volatile("s_waitcnt vmcnt(0)" ::: "memory");
  __builtin_amdgcn_s_barrier();
  __builtin_amdgcn_sched_barrier(0);

  for (int t = 0; t < 8; ++t) {
    int c = t & 1;
    if (t + 1 < 8) stage8(Qb, Kb, smem, c ^ 1, t + 1, 512, w, lr, sl);
    const bf16* At = smem + c * 32768;
    const bf16* Bt = At + 16384;
    __builtin_amdgcn_s_setprio(1);
    #pragma unroll
    for (int kk = 0; kk < 2; ++kk) {
      int ps = (kk * 4 + lg) ^ swz;
      bf16x8 a[8], b[4];
      #pragma unroll
      for (int i = 0; i < 8; ++i)
        a[i] = *(const bf16x8*)&At[(wm2 * 128 + i * 16 + l15) * 64 + ps * 8];
      #pragma unroll
      for (int j = 0; j < 4; ++j)
        b[j] = *(const bf16x8*)&Bt[(wn4 * 64 + j * 16 + l15) * 64 + ps * 8];
      #pragma unroll
      for (int i = 0; i < 8; ++i)
        #pragma unroll
        for (int j = 0; j < 4; ++j)
          acc[i][j] = __builtin_amdgcn_mfma_f32_16x16x32_bf16(a[i], b[j], acc[i][j], 0, 0, 0);
    }
    __builtin_amdgcn_s_setprio(0);
    asm volatile("s_waitcnt vmcnt(0)" ::: "memory");
    __builtin_amdgcn_s_barrier();
    __builtin_amdgcn_sched_barrier(0);
  }

  const float SCALE = 0.04419417382415922f;  // 1/sqrt(512)
  bf16* Sb = S + (size_t)batch * 1024 * 1024;
  #pragma unroll
  for (int i = 0; i < 8; ++i)
    #pragma unroll
    for (int j = 0; j < 4; ++j)
      #pragma unroll
      for (int r = 0; r < 4; ++r) {
        int row = tm * 256 + wm2 * 128 + i * 16 + lg * 4 + r;
        int col = tn * 256 + wn4 * 64 + j * 16 + l15;
        Sb[(size_t)row * 1024 + col] = __float2bfloat16(acc[i][j][r] * SCALE);
      }
}

// ---------------- row stats: per row m = max, rcp = 1/sum(exp(s-m)) ----------------
__global__ __launch_bounds__(256) void row_stats(const bf16* __restrict__ S, float2* __restrict__ pstats) {
  int l = threadIdx.x & 63;
  size_t row = (size_t)blockIdx.x * 4 + (threadIdx.x >> 6);
  const bf16* p = S + row * 1024 + l * 16;
  bf16x8 s0 = *(const bf16x8*)p;
  bf16x8 s1 = *(const bf16x8*)(p + 8);
  float f[16];
  #pragma unroll
  for (int i = 0; i < 8; ++i) { f[i] = b2f((unsigned short)s0[i]); f[8 + i] = b2f((unsigned short)s1[i]); }
  float m = f[0];
  #pragma unroll
  for (int i = 1; i < 16; ++i) m = fmaxf(m, f[i]);
  for (int d = 1; d < 64; d <<= 1) m = fmaxf(m, __shfl_xor(m, d));
  float sum = 0.f;
  #pragma unroll
  for (int i = 0; i < 16; ++i) sum += __expf(f[i] - m);
  for (int d = 1; d < 64; d <<= 1) sum += __shfl_xor(sum, d);
  if (l == 0) {
    float2 st; st.x = m; st.y = 1.0f / sum;
    pstats[row] = st;
  }
}

// ---------------- batched PV (A = exp(S-m)*rcp staged in-reg; B = Vt) ----------------
__global__ __launch_bounds__(512, 2) void pv_gemm(const bf16* __restrict__ S, const bf16* __restrict__ vt,
                                                  const float2* __restrict__ pstats,
                                                  bf16* __restrict__ y) {
  __shared__ bf16 smem[65536];         // 128 KiB: 2 bufs x (A 32K + B 32K)
  int tid = threadIdx.x;
  int bid = (blockIdx.x & 7) * 64 + (blockIdx.x >> 3);     // XCD swizzle (512 % 8 == 0)
  int batch = bid >> 3, bq = (bid >> 1) & 3, bd = bid & 1;
  const bf16* Pb = S + (size_t)batch * 1024 * 1024 + (size_t)bq * 256 * 1024;
  const bf16* Vb = vt + (size_t)batch * 512 * 1024 + (size_t)bd * 256 * 1024;
  int w = tid >> 6, l = tid & 63, l15 = l & 15, lg = l >> 4;
  int wm2 = w >> 2, wn4 = w & 3;
  int lr = l >> 3, sl = (l & 7) ^ lr, swz = l15 & 7;
  f32x4 z4 = {0.f, 0.f, 0.f, 0.f};
  f32x4 acc[8][4];
  for (int i = 0; i < 8; ++i) for (int j = 0; j < 4; ++j) acc[i][j] = z4;

  float m4[4], r4[4];
  #pragma unroll
  for (int p = 0; p < 4; ++p) {
    float2 st = pstats[(size_t)batch * 1024 + bq * 256 + p * 64 + w * 8 + lr];
    m4[p] = st.x; r4[p] = st.y;
  }

  bf16x8 areg[4];
  #define PV_ISSUE(tt, cc)                                                        \
    {                                                                             \
      _Pragma("unroll")                                                           \
      for (int p = 0; p < 4; ++p)                                                 \
        areg[p] = *(const bf16x8*)&Pb[(size_t)(p * 64 + w * 8 + lr) * 1024 +      \
                                      (tt) * 64 + sl * 8];                        \
      _Pragma("unroll")                                                           \
      for (int p = 0; p < 4; ++p)                                                 \
        gload_lds16(Vb + (size_t)(p * 64 + w * 8 + lr) * 1024 + (tt) * 64 + sl * 8, \
                    (char*)smem + (cc) * 65536 + 32768 + p * 8192 + w * 1024);    \
    }
  #define PV_WRITE_A(cc)                                                          \
    {                                                                             \
      _Pragma("unroll")                                                           \
      for (int p = 0; p < 4; ++p) {                                               \
        bf16x8 o;                                                                 \
        _Pragma("unroll")                                                         \
        for (int e = 0; e < 8; ++e) {                                             \
          float fv = b2f((unsigned short)areg[p][e]);                             \
          o[e] = (short)f2b(__expf(fv - m4[p]) * r4[p]);                          \
        }                                                                         \
        *(bf16x8*)((char*)smem + (cc) * 65536 + p * 8192 + w * 1024 + l * 16) = o; \
      }                                                                           \
    }

  PV_ISSUE(0, 0);
  asm volatile("s_waitcnt vmcnt(0)" ::: "memory");
  PV_WRITE_A(0);
  asm volatile("s_waitcnt lgkmcnt(0)" ::: "memory");
  __builtin_amdgcn_s_barrier();
  __builtin_amdgcn_sched_barrier(0);

  for (int t = 0; t < 16; ++t) {
    int c = t & 1;
    if (t + 1 < 16) PV_ISSUE(t + 1, c ^ 1);
    const bf16* At = smem + c * 32768;
    const bf16* Bt = At + 16384;
    __builtin_amdgcn_s_setprio(1);
    #pragma unroll
    for (int kk = 0; kk < 2; ++kk) {
      int ps = (kk * 4 + lg) ^ swz;
      bf16x8 a[8], b[4];
      #pragma unroll
      for (int i = 0; i < 8; ++i)
        a[i] = *(const bf16x8*)&At[(wm2 * 128 + i * 16 + l15) * 64 + ps * 8];
      #pragma unroll
      for (int j = 0; j < 4; ++j)
        b[j] = *(const bf16x8*)&Bt[(wn4 * 64 + j * 16 + l15) * 64 + ps * 8];
      #pragma unroll
      for (int i = 0; i < 8; ++i)
        #pragma unroll
        for (int j = 0; j < 4; ++j)
          acc[i][j] = __builtin_amdgcn_mfma_f32_16x16x32_bf16(a[i], b[j], acc[i][j], 0, 0, 0);
    }
    __builtin_amdgcn_s_setprio(0);
    asm volatile("s_waitcnt vmcnt(0)" ::: "memory");
    if (t + 1 < 16) PV_WRITE_A(c ^ 1);
    asm volatile("s_waitcnt lgkmcnt(0)" ::: "memory");
    __builtin_amdgcn_s_barrier();
    __builtin_amdgcn_sched_barrier(0);
  }

  // epilogue: direct channels-last stores (16B runs per 8 lanes)
  int t2 = batch >> 3, h = batch & 7;
  #pragma unroll
  for (int i = 0; i < 8; ++i)
    #pragma unroll
    for (int j = 0; j < 4; ++j)
      #pragma unroll
      for (int r = 0; r < 4; ++r) {
        int win = bq * 256 + wm2 * 128 + i * 16 + lg * 4 + r;
        int dp = bd * 256 + wn4 * 64 + j * 16 + l15;
        int jj = dp & 7, pyix = dp >> 3;
        int gy = win >> 5, gx = win & 31;
        int Y = gy * 8 + (pyix >> 3), X = gx * 8 + (pyix & 7);
        y[(((size_t)t2 * 256 + Y) * 256 + X) * 64 + h * 8 + jj] = __float2bfloat16(acc[i][j][r]);
      }
}

// ---------------- final full-image conv + residual -> f32 out ----------------
__global__ __launch_bounds__(256, 4) void out_conv(const bf16* __restrict__ yimg, const bf16* __restrict__ wot,
                                                   const float* __restrict__ bo, float* __restrict__ out) {
  __shared__ bf16 yp[324 * 76];        // [py*18+px][ci pad76]
  int tid = threadIdx.x, bid = blockIdx.x;
  int t = bid >> 8, tile = bid & 255;
  int y0 = (tile >> 4) * 16, x0 = (tile & 15) * 16;
  const bf16* yb = yimg + (size_t)t * 256 * 256 * 64;

  for (int e = tid; e < 324 * 8; e += 256) {
    int seg = e & 7, pos = e >> 3;
    int ppx = pos % 18, ppy = pos / 18;
    int gy = y0 + ppy - 1, gx = x0 + ppx - 1;
    bf16x8 val = {0, 0, 0, 0, 0, 0, 0, 0};
    if ((unsigned)gy < 256u && (unsigned)gx < 256u)
      val = *(const bf16x8*)&yb[((size_t)gy * 256 + gx) * 64 + seg * 8];
    *(bf16x8*)&yp[pos * 76 + seg * 8] = val;
  }
  __syncthreads();

  int wv = tid >> 6, l = tid & 63, l15 = l & 15, lg = l >> 4;
  int wm = wv & 1, wn = wv >> 1;
  f32x4 z4 = {0.f, 0.f, 0.f, 0.f};
  f32x4 acc[2][8];
  for (int i = 0; i < 2; ++i) for (int j = 0; j < 8; ++j) acc[i][j] = z4;

  #pragma unroll
  for (int s9 = 0; s9 < 9; ++s9) {
    const int dy = s9 / 3, dx = s9 % 3;
    #pragma unroll
    for (int half = 0; half < 2; ++half) {
      bf16x8 a[2];
      #pragma unroll
      for (int mt = 0; mt < 2; ++mt)
        a[mt] = *(const bf16x8*)&wot[((size_t)s9 * 64 + wm * 32 + mt * 16 + l15) * 64 + half * 32 + lg * 8];
      #pragma unroll
      for (int nt = 0; nt < 8; ++nt) {
        int ty = wn * 8 + nt;
        bf16x8 b = *(const bf16x8*)&yp[((ty + dy) * 18 + l15 + dx) * 76 + half * 32 + lg * 8];
        #pragma unroll
        for (int mt = 0; mt < 2; ++mt)
          acc[mt][nt] = __builtin_amdgcn_mfma_f32_16x16x32_bf16(a[mt], b, acc[mt][nt], 0, 0, 0);
      }
    }
  }

  float* ob = out + (size_t)t * 64 * 65536;
  float bias[2][4];
  #pragma unroll
  for (int mt = 0; mt < 2; ++mt)
    #pragma unroll
    for (int r = 0; r < 4; ++r) bias[mt][r] = bo[wm * 32 + mt * 16 + lg * 4 + r];
  #pragma unroll
  for (int mt = 0; mt < 2; ++mt)
    #pragma unroll
    for (int nt = 0; nt < 8; ++nt) {
      int ty = wn * 8 + nt;
      #pragma unroll
      for (int r = 0; r < 4; ++r) {
        int co = wm * 32 + mt * 16 + lg * 4 + r;
        float res = b2f(*(const unsigned short*)&yp[((ty + 1) * 18 + l15 + 1) * 76 + co]);
        ob[(size_t)co * 65536 + (size_t)(y0 + ty) * 256 + x0 + l15] = res + acc[mt][nt][r] + bias[mt][r];
      }
    }
}

// ---------------- launcher ----------------
extern "C" void kernel_launch(void* const* d_in, const int* in_sizes, int n_in,
                              void* d_out, int out_size, void* d_ws, size_t ws_size,
                              hipStream_t stream) {
  const float* x  = (const float*)d_in[0];
  const float* Wq = (const float*)d_in[1];
  const float* bq = (const float*)d_in[2];
  const float* Wk = (const float*)d_in[3];
  const float* bk = (const float*)d_in[4];
  const float* Wv = (const float*)d_in[5];
  const float* bv = (const float*)d_in[6];
  const float* Wo = (const float*)d_in[7];
  const float* bo = (const float*)d_in[8];
  float* out = (float*)d_out;

  char* ws = (char*)d_ws;
  bf16* wt  = (bf16*)(ws + 0);
  bf16* wot = (bf16*)(ws + 110592);
  bf16* q   = (bf16*)(ws + 262144);              // reused as y_img after qk_gemm
  bf16* k   = (bf16*)(ws + 67371008);
  float2* pstats = (float2*)(ws + 67371008);     // overlaps k (dead after qk_gemm)
  bf16* S   = (bf16*)(ws + 134479872);
  bf16* vt  = (bf16*)(ws + 268697600);
  bf16* y   = (bf16*)(ws + 262144);              // channels-last [8][256][256][64]
  bf16* v   = S;                                 // v staged where S will go (dead before qk)
  // requires ws_size >= 335,806,464 bytes

  prep_w<<<216, 256, 0, stream>>>(Wq, Wk, Wv, Wo, wt, wot);
  qkv_conv<<<4096, 256, 0, stream>>>(x, wt, bq, bk, bv, q, k, v);
  transpose_v<<<8192, 256, 0, stream>>>(v, vt);
  qk_gemm<<<1024, 512, 0, stream>>>(q, k, S);
  row_stats<<<16384, 256, 0, stream>>>(S, pstats);
  pv_gemm<<<512, 512, 0, stream>>>(S, vt, pstats, y);
  out_conv<<<2048, 256, 0, stream>>>(y, wot, bo, out);
}